// Round 3
// baseline (133.215 us; speedup 1.0000x reference)
//
#include <hip/hip_runtime.h>

#define NB    32      // batch
#define CIN   512     // IN_CH
#define MID2  1024    // MAX_MID*2
#define MID   512     // MAX_MID
#define HW    4096    // 64*64

// ---------------- Kernel 1: global average pool ----------------
// 4096 blocks x 256 threads; each of the 4 waves owns one (b,c) row:
// 16 independent float4 loads per lane, shuffle-only reduce, no LDS.
__global__ __launch_bounds__(256) void k_gap(const float* __restrict__ x,
                                             float* __restrict__ gap) {
    const int row  = blockIdx.x * 4 + (threadIdx.x >> 6);   // b*CIN + c
    const int lane = threadIdx.x & 63;
    const float4* x4 = (const float4*)(x + (size_t)row * HW);
    float s0 = 0.f, s1 = 0.f, s2 = 0.f, s3 = 0.f;
#pragma unroll
    for (int it = 0; it < 4; ++it) {
        float4 a = x4[(4 * it + 0) * 64 + lane];
        float4 b = x4[(4 * it + 1) * 64 + lane];
        float4 c = x4[(4 * it + 2) * 64 + lane];
        float4 d = x4[(4 * it + 3) * 64 + lane];
        s0 += (a.x + a.y) + (a.z + a.w);
        s1 += (b.x + b.y) + (b.z + b.w);
        s2 += (c.x + c.y) + (c.z + c.w);
        s3 += (d.x + d.y) + (d.z + d.w);
    }
    float s = (s0 + s1) + (s2 + s3);
    for (int off = 32; off; off >>= 1) s += __shfl_down(s, off, 64);
    if (lane == 0) gap[row] = s * (1.0f / HW);
}

// ---------------- Kernel 2: fused fc1+ReLU+fc2+sigmoid ----------------
// 32 blocks (one per batch) x 1024 threads (16 waves).
// Phase A: wave w computes h[j], j = w*64..w*64+63 (K=512: 8 elems/lane in regs).
// Phase B: wave w computes scores[m], m = w*32..w*32+31 (K=1024: 16 elems/lane).
// Also emits the per-row score sum (fixed-order reduce -> deterministic).
__global__ __launch_bounds__(1024) void k_fc(const float* __restrict__ gap,
                                             const float* __restrict__ w1,
                                             const float* __restrict__ b1,
                                             const float* __restrict__ w2,
                                             const float* __restrict__ b2,
                                             float* __restrict__ scores,
                                             float* __restrict__ sums) {
    const int b = blockIdx.x;
    const int t = threadIdx.x, wid = t >> 6, lane = t & 63;
    __shared__ float hsh[MID2];
    __shared__ float srow[MID];
    __shared__ float red[8];

    // gap slice for this lane, reused across all 64 phase-A outputs
    const float4 g0 = *(const float4*)(gap + b * CIN + lane * 8);
    const float4 g1 = *(const float4*)(gap + b * CIN + lane * 8 + 4);

    // ---- Phase A: fc1 + ReLU ----
#pragma unroll 2
    for (int jo = 0; jo < 64; ++jo) {
        const int j = wid * 64 + jo;
        const float* w = w1 + (size_t)j * CIN + lane * 8;
        const float4 a = *(const float4*)w;
        const float4 c = *(const float4*)(w + 4);
        float s = (a.x * g0.x + a.y * g0.y) + (a.z * g0.z + a.w * g0.w) +
                  (c.x * g1.x + c.y * g1.y) + (c.z * g1.z + c.w * g1.w);
        for (int off = 32; off; off >>= 1) s += __shfl_down(s, off, 64);
        if (lane == 0) hsh[j] = fmaxf(s + b1[j], 0.f);
    }
    __syncthreads();

    // h slice for this lane, reused across all 32 phase-B outputs
    const float4* h4 = (const float4*)(hsh + lane * 16);
    const float4 h0 = h4[0], h1 = h4[1], h2 = h4[2], h3 = h4[3];

    // ---- Phase B: fc2 + sigmoid ----
#pragma unroll 2
    for (int mo = 0; mo < 32; ++mo) {
        const int m = wid * 32 + mo;
        const float4* w = (const float4*)(w2 + (size_t)m * MID2 + lane * 16);
        const float4 a = w[0], c = w[1], d = w[2], e = w[3];
        float s = (a.x * h0.x + a.y * h0.y) + (a.z * h0.z + a.w * h0.w) +
                  (c.x * h1.x + c.y * h1.y) + (c.z * h1.z + c.w * h1.w) +
                  (d.x * h2.x + d.y * h2.y) + (d.z * h2.z + d.w * h2.w) +
                  (e.x * h3.x + e.y * h3.y) + (e.z * h3.z + e.w * h3.w);
        for (int off = 32; off; off >>= 1) s += __shfl_down(s, off, 64);
        if (lane == 0) {
            const float v = s + b2[m];
            const float sc = 1.0f / (1.0f + __expf(-v));
            srow[m] = sc;
            scores[b * MID + m] = sc;
        }
    }
    __syncthreads();

    // ---- row sum (deterministic fixed order) ----
    if (t < MID) {
        float s = srow[t];
        for (int off = 32; off; off >>= 1) s += __shfl_down(s, off, 64);
        if (lane == 0) red[wid] = s;
    }
    __syncthreads();
    if (t == 0) {
        sums[b] = ((red[0] + red[1]) + (red[2] + red[3])) +
                  ((red[4] + red[5]) + (red[6] + red[7]));
    }
}

// ---------------- Kernel 3: mean -> k -> threshold -> mask ----------------
// 32 blocks x 512 threads. Global mean from the 32 per-row sums (fixed order,
// identical in every block). Rank-count selection, tie-safe.
__global__ __launch_bounds__(512) void k_mask(const float* __restrict__ scores,
                                              const float* __restrict__ sums,
                                              float* __restrict__ out) {
    __shared__ float srow[MID];
    __shared__ float thr;
    const int b = blockIdx.x, t = threadIdx.x;

    float tot = 0.f;
#pragma unroll
    for (int i = 0; i < NB; ++i) tot += sums[i];
    const float mean = tot / (float)(NB * MID);
    const float scale = fminf(fmaxf(mean, 0.25f), 1.0f);
    int k = (int)ceilf((float)MID * scale);
    k = min(max(k, 128), MID);                        // k_min = max(4, 512/4) = 128

    const float v = scores[b * MID + t];
    srow[t] = v;
    __syncthreads();

    const float4* srow4 = (const float4*)srow;
    int gt = 0, ge = 0;
    for (int i = 0; i < MID / 4; ++i) {
        const float4 u = srow4[i];   // uniform addr -> LDS broadcast
        gt += (u.x > v) + (u.y > v) + (u.z > v) + (u.w > v);
        ge += (u.x >= v) + (u.y >= v) + (u.z >= v) + (u.w >= v);
    }
    if (gt < k && ge >= k) thr = v;   // all satisfying threads hold same value
    __syncthreads();
    out[b * MID + t] = (v >= thr) ? 1.0f : 0.0f;
    if (b == 0 && t == 0) out[NB * MID] = (float)k;
}

extern "C" void kernel_launch(void* const* d_in, const int* in_sizes, int n_in,
                              void* d_out, int out_size, void* d_ws, size_t ws_size,
                              hipStream_t stream) {
    const float* x  = (const float*)d_in[0];
    const float* w1 = (const float*)d_in[1];
    const float* b1 = (const float*)d_in[2];
    const float* w2 = (const float*)d_in[3];
    const float* b2 = (const float*)d_in[4];
    float* out = (float*)d_out;

    float* gap    = (float*)d_ws;            // NB*CIN = 16384 floats
    float* scores = gap + NB * CIN;          // NB*MID = 16384 floats
    float* sums   = scores + NB * MID;       // NB floats

    k_gap <<<NB * CIN / 4, 256,  0, stream>>>(x, gap);
    k_fc  <<<NB,           1024, 0, stream>>>(gap, w1, b1, w2, b2, scores, sums);
    k_mask<<<NB,           512,  0, stream>>>(scores, sums, out);
}

// Round 5
// 69.610 us; speedup vs baseline: 1.9137x; 1.9137x over previous
//
#include <hip/hip_runtime.h>

#define NB    32      // batch
#define CIN   512     // IN_CH
#define MID2  1024    // MAX_MID*2
#define MID   512     // MAX_MID
#define HW    4096    // 64*64

typedef float f32x4 __attribute__((ext_vector_type(4)));

// ---------------- Kernel 1: global average pool ----------------
// 4096 blocks x 256 threads; each of the 4 waves owns one (b,c) row:
// 16 independent nontemporal float4 loads per lane (x is streamed once --
// keep it out of L2/L3 so the MLP weights stay cached), shuffle-only reduce.
__global__ __launch_bounds__(256) void k_gap(const float* __restrict__ x,
                                             float* __restrict__ gap) {
    const int row  = blockIdx.x * 4 + (threadIdx.x >> 6);   // b*CIN + c
    const int lane = threadIdx.x & 63;
    const f32x4* x4 = (const f32x4*)(x + (size_t)row * HW);
    float s0 = 0.f, s1 = 0.f, s2 = 0.f, s3 = 0.f;
#pragma unroll
    for (int it = 0; it < 4; ++it) {
        f32x4 a = __builtin_nontemporal_load(&x4[(4 * it + 0) * 64 + lane]);
        f32x4 b = __builtin_nontemporal_load(&x4[(4 * it + 1) * 64 + lane]);
        f32x4 c = __builtin_nontemporal_load(&x4[(4 * it + 2) * 64 + lane]);
        f32x4 d = __builtin_nontemporal_load(&x4[(4 * it + 3) * 64 + lane]);
        s0 += (a.x + a.y) + (a.z + a.w);
        s1 += (b.x + b.y) + (b.z + b.w);
        s2 += (c.x + c.y) + (c.z + c.w);
        s3 += (d.x + d.y) + (d.z + d.w);
    }
    float s = (s0 + s1) + (s2 + s3);
    for (int off = 32; off; off >>= 1) s += __shfl_down(s, off, 64);
    if (lane == 0) gap[row] = s * (1.0f / HW);
}

// ---------------- Kernel 2: fc1 + ReLU ----------------
// 2048 blocks x 256 threads; each wave computes 4 consecutive outputs of the
// same batch row, reusing the gap slice held in registers (4x less L2 traffic).
__global__ __launch_bounds__(256) void k_fc1(const float* __restrict__ gap,
                                             const float* __restrict__ w1,
                                             const float* __restrict__ b1,
                                             float* __restrict__ h) {
    const int wid = threadIdx.x >> 6, lane = threadIdx.x & 63;
    const int o4 = (blockIdx.x * 4 + wid) * 4;        // first of 4 outputs
    const int b  = o4 >> 10;                          // o4 / MID2
    const int j0 = o4 & (MID2 - 1);
    const float* g = gap + b * CIN + lane * 8;
    const float4 g0 = *(const float4*)g;
    const float4 g1 = *(const float4*)(g + 4);
    float s[4];
#pragma unroll
    for (int r = 0; r < 4; ++r) {
        const float* w = w1 + (size_t)(j0 + r) * CIN + lane * 8;
        const float4 a = *(const float4*)w;
        const float4 c = *(const float4*)(w + 4);
        s[r] = (a.x * g0.x + a.y * g0.y) + (a.z * g0.z + a.w * g0.w) +
               (c.x * g1.x + c.y * g1.y) + (c.z * g1.z + c.w * g1.w);
    }
#pragma unroll
    for (int r = 0; r < 4; ++r)
        for (int off = 32; off; off >>= 1) s[r] += __shfl_down(s[r], off, 64);
    if (lane == 0) {
#pragma unroll
        for (int r = 0; r < 4; ++r) h[o4 + r] = fmaxf(s[r] + b1[j0 + r], 0.f);
    }
}

// ---------------- Kernel 3: fc2 + sigmoid ----------------
// 1024 blocks x 256 threads; each wave computes 4 consecutive outputs,
// reusing the h slice (16 floats/lane) across the 4 weight rows.
__global__ __launch_bounds__(256) void k_fc2(const float* __restrict__ h,
                                             const float* __restrict__ w2,
                                             const float* __restrict__ b2,
                                             float* __restrict__ scores) {
    const int wid = threadIdx.x >> 6, lane = threadIdx.x & 63;
    const int o4 = (blockIdx.x * 4 + wid) * 4;        // first of 4 outputs
    const int b  = o4 >> 9;                           // o4 / MID
    const int m0 = o4 & (MID - 1);
    const float4* h4 = (const float4*)(h + b * MID2 + lane * 16);
    const float4 h0 = h4[0], h1 = h4[1], h2 = h4[2], h3 = h4[3];
    float s[4];
#pragma unroll
    for (int r = 0; r < 4; ++r) {
        const float4* w = (const float4*)(w2 + (size_t)(m0 + r) * MID2 + lane * 16);
        const float4 a = w[0], c = w[1], d = w[2], e = w[3];
        s[r] = (a.x * h0.x + a.y * h0.y) + (a.z * h0.z + a.w * h0.w) +
               (c.x * h1.x + c.y * h1.y) + (c.z * h1.z + c.w * h1.w) +
               (d.x * h2.x + d.y * h2.y) + (d.z * h2.z + d.w * h2.w) +
               (e.x * h3.x + e.y * h3.y) + (e.z * h3.z + e.w * h3.w);
    }
#pragma unroll
    for (int r = 0; r < 4; ++r)
        for (int off = 32; off; off >>= 1) s[r] += __shfl_down(s[r], off, 64);
    if (lane == 0) {
#pragma unroll
        for (int r = 0; r < 4; ++r) {
            const float v = s[r] + b2[m0 + r];
            scores[o4 + r] = 1.0f / (1.0f + __expf(-v));
        }
    }
}

// ---------------- Kernel 4: fused mean->k->threshold->mask ----------------
// 32 blocks x 512 threads. Every block redundantly computes the global mean
// (identical FP order -> identical k in all blocks, deterministic), then
// rank-count selection for its own row. Tie-safe: the k-th largest value v
// satisfies count(>v) < k <= count(>=v).
__global__ __launch_bounds__(512) void k_mask(const float* __restrict__ scores,
                                              float* __restrict__ out) {
    __shared__ float srow[MID];
    __shared__ float red[8];
    __shared__ float thr;
    const int b = blockIdx.x, t = threadIdx.x;

    // global mean over all NB*MID scores (L2-resident, 64 KiB)
    float s = 0.f;
#pragma unroll
    for (int i = 0; i < NB * MID / 512; ++i) s += scores[i * 512 + t];
    for (int off = 32; off; off >>= 1) s += __shfl_down(s, off, 64);
    const int wid = t >> 6, lane = t & 63;
    if (lane == 0) red[wid] = s;

    const float v = scores[b * MID + t];
    srow[t] = v;
    __syncthreads();

    const float tot = ((red[0] + red[1]) + (red[2] + red[3])) +
                      ((red[4] + red[5]) + (red[6] + red[7]));
    const float mean = tot / (float)(NB * MID);
    const float scale = fminf(fmaxf(mean, 0.25f), 1.0f);
    int k = (int)ceilf((float)MID * scale);
    k = min(max(k, 128), MID);                        // k_min = max(4, 512/4) = 128

    // rank-count vs own value, float4 LDS reads (uniform addr -> broadcast)
    const float4* srow4 = (const float4*)srow;
    int gt = 0, ge = 0;
    for (int i = 0; i < MID / 4; ++i) {
        const float4 u = srow4[i];
        gt += (u.x > v) + (u.y > v) + (u.z > v) + (u.w > v);
        ge += (u.x >= v) + (u.y >= v) + (u.z >= v) + (u.w >= v);
    }
    if (gt < k && ge >= k) thr = v;   // all satisfying threads hold the same value
    __syncthreads();
    out[b * MID + t] = (v >= thr) ? 1.0f : 0.0f;
    if (b == 0 && t == 0) out[NB * MID] = (float)k;
}

extern "C" void kernel_launch(void* const* d_in, const int* in_sizes, int n_in,
                              void* d_out, int out_size, void* d_ws, size_t ws_size,
                              hipStream_t stream) {
    const float* x  = (const float*)d_in[0];
    const float* w1 = (const float*)d_in[1];
    const float* b1 = (const float*)d_in[2];
    const float* w2 = (const float*)d_in[3];
    const float* b2 = (const float*)d_in[4];
    float* out = (float*)d_out;

    float* gap    = (float*)d_ws;            // NB*CIN  = 16384 floats
    float* h      = gap + NB * CIN;          // NB*MID2 = 32768 floats
    float* scores = h + NB * MID2;           // NB*MID  = 16384 floats

    k_gap <<<NB * CIN / 4,       256, 0, stream>>>(x, gap);
    k_fc1 <<<NB * MID2 / (4*4),  256, 0, stream>>>(gap, w1, b1, h);
    k_fc2 <<<NB * MID  / (4*4),  256, 0, stream>>>(h, w2, b2, scores);
    k_mask<<<NB,                 512, 0, stream>>>(scores, out);
}

// Round 6
// 67.253 us; speedup vs baseline: 1.9808x; 1.0350x over previous
//
#include <hip/hip_runtime.h>

#define NB    32      // batch
#define CIN   512     // IN_CH
#define MID2  1024    // MAX_MID*2
#define MID   512     // MAX_MID
#define HW    4096    // 64*64

typedef float f32x4 __attribute__((ext_vector_type(4)));

// ---------------- Kernel 1: global average pool ----------------
// 8192 blocks x 256 threads, TWO rows per block: 8 independent nontemporal
// float4 loads per thread (32 VGPR of data), __launch_bounds__(256,8) pins
// VGPR <= 64 so occupancy hits 32 waves/CU -- max memory-level parallelism.
__global__ __launch_bounds__(256, 8) void k_gap(const float* __restrict__ x,
                                                float* __restrict__ gap) {
    const int r0 = blockIdx.x * 2;
    const int t  = threadIdx.x;
    const f32x4* p0 = (const f32x4*)(x + (size_t)r0 * HW);
    const f32x4* p1 = (const f32x4*)(x + (size_t)(r0 + 1) * HW);
    float a0 = 0.f, a1 = 0.f;
#pragma unroll
    for (int i = 0; i < 4; ++i) {
        f32x4 u = __builtin_nontemporal_load(&p0[i * 256 + t]);
        f32x4 v = __builtin_nontemporal_load(&p1[i * 256 + t]);
        a0 += (u.x + u.y) + (u.z + u.w);
        a1 += (v.x + v.y) + (v.z + v.w);
    }
    for (int off = 32; off; off >>= 1) {
        a0 += __shfl_down(a0, off, 64);
        a1 += __shfl_down(a1, off, 64);
    }
    __shared__ float w0[4], w1[4];
    const int wid = t >> 6, lane = t & 63;
    if (lane == 0) { w0[wid] = a0; w1[wid] = a1; }
    __syncthreads();
    if (t == 0) gap[r0]     = ((w0[0] + w0[1]) + (w0[2] + w0[3])) * (1.0f / HW);
    if (t == 1) gap[r0 + 1] = ((w1[0] + w1[1]) + (w1[2] + w1[3])) * (1.0f / HW);
}

// ---------------- Kernel 2: fc1 + ReLU ----------------
// 2048 blocks x 256 threads; each wave computes 4 consecutive outputs of the
// same batch row, reusing the gap slice held in registers.
__global__ __launch_bounds__(256) void k_fc1(const float* __restrict__ gap,
                                             const float* __restrict__ w1,
                                             const float* __restrict__ b1,
                                             float* __restrict__ h) {
    const int wid = threadIdx.x >> 6, lane = threadIdx.x & 63;
    const int o4 = (blockIdx.x * 4 + wid) * 4;        // first of 4 outputs
    const int b  = o4 >> 10;                          // o4 / MID2
    const int j0 = o4 & (MID2 - 1);
    const float* g = gap + b * CIN + lane * 8;
    const float4 g0 = *(const float4*)g;
    const float4 g1 = *(const float4*)(g + 4);
    float s[4];
#pragma unroll
    for (int r = 0; r < 4; ++r) {
        const float* w = w1 + (size_t)(j0 + r) * CIN + lane * 8;
        const float4 a = *(const float4*)w;
        const float4 c = *(const float4*)(w + 4);
        s[r] = (a.x * g0.x + a.y * g0.y) + (a.z * g0.z + a.w * g0.w) +
               (c.x * g1.x + c.y * g1.y) + (c.z * g1.z + c.w * g1.w);
    }
#pragma unroll
    for (int r = 0; r < 4; ++r)
        for (int off = 32; off; off >>= 1) s[r] += __shfl_down(s[r], off, 64);
    if (lane == 0) {
#pragma unroll
        for (int r = 0; r < 4; ++r) h[o4 + r] = fmaxf(s[r] + b1[j0 + r], 0.f);
    }
}

// ---------------- Kernel 3: fc2 + sigmoid ----------------
// 1024 blocks x 256 threads; each wave computes 4 consecutive outputs,
// reusing the h slice (16 floats/lane) across the 4 weight rows.
__global__ __launch_bounds__(256) void k_fc2(const float* __restrict__ h,
                                             const float* __restrict__ w2,
                                             const float* __restrict__ b2,
                                             float* __restrict__ scores) {
    const int wid = threadIdx.x >> 6, lane = threadIdx.x & 63;
    const int o4 = (blockIdx.x * 4 + wid) * 4;        // first of 4 outputs
    const int b  = o4 >> 9;                           // o4 / MID
    const int m0 = o4 & (MID - 1);
    const float4* h4 = (const float4*)(h + b * MID2 + lane * 16);
    const float4 h0 = h4[0], h1 = h4[1], h2 = h4[2], h3 = h4[3];
    float s[4];
#pragma unroll
    for (int r = 0; r < 4; ++r) {
        const float4* w = (const float4*)(w2 + (size_t)(m0 + r) * MID2 + lane * 16);
        const float4 a = w[0], c = w[1], d = w[2], e = w[3];
        s[r] = (a.x * h0.x + a.y * h0.y) + (a.z * h0.z + a.w * h0.w) +
               (c.x * h1.x + c.y * h1.y) + (c.z * h1.z + c.w * h1.w) +
               (d.x * h2.x + d.y * h2.y) + (d.z * h2.z + d.w * h2.w) +
               (e.x * h3.x + e.y * h3.y) + (e.z * h3.z + e.w * h3.w);
    }
#pragma unroll
    for (int r = 0; r < 4; ++r)
        for (int off = 32; off; off >>= 1) s[r] += __shfl_down(s[r], off, 64);
    if (lane == 0) {
#pragma unroll
        for (int r = 0; r < 4; ++r) {
            const float v = s[r] + b2[m0 + r];
            scores[o4 + r] = 1.0f / (1.0f + __expf(-v));
        }
    }
}

// ---------------- Kernel 4: fused mean->k->threshold->mask ----------------
// 32 blocks x 512 threads. Every block redundantly computes the global mean
// (identical FP order -> identical k in all blocks, deterministic), then
// rank-count selection for its own row. Tie-safe.
__global__ __launch_bounds__(512) void k_mask(const float* __restrict__ scores,
                                              float* __restrict__ out) {
    __shared__ float srow[MID];
    __shared__ float red[8];
    __shared__ float thr;
    const int b = blockIdx.x, t = threadIdx.x;

    float s = 0.f;
#pragma unroll
    for (int i = 0; i < NB * MID / 512; ++i) s += scores[i * 512 + t];
    for (int off = 32; off; off >>= 1) s += __shfl_down(s, off, 64);
    const int wid = t >> 6, lane = t & 63;
    if (lane == 0) red[wid] = s;

    const float v = scores[b * MID + t];
    srow[t] = v;
    __syncthreads();

    const float tot = ((red[0] + red[1]) + (red[2] + red[3])) +
                      ((red[4] + red[5]) + (red[6] + red[7]));
    const float mean = tot / (float)(NB * MID);
    const float scale = fminf(fmaxf(mean, 0.25f), 1.0f);
    int k = (int)ceilf((float)MID * scale);
    k = min(max(k, 128), MID);                        // k_min = max(4, 512/4) = 128

    const float4* srow4 = (const float4*)srow;
    int gt = 0, ge = 0;
    for (int i = 0; i < MID / 4; ++i) {
        const float4 u = srow4[i];    // uniform addr -> LDS broadcast
        gt += (u.x > v) + (u.y > v) + (u.z > v) + (u.w > v);
        ge += (u.x >= v) + (u.y >= v) + (u.z >= v) + (u.w >= v);
    }
    if (gt < k && ge >= k) thr = v;   // all satisfying threads hold the same value
    __syncthreads();
    out[b * MID + t] = (v >= thr) ? 1.0f : 0.0f;
    if (b == 0 && t == 0) out[NB * MID] = (float)k;
}

extern "C" void kernel_launch(void* const* d_in, const int* in_sizes, int n_in,
                              void* d_out, int out_size, void* d_ws, size_t ws_size,
                              hipStream_t stream) {
    const float* x  = (const float*)d_in[0];
    const float* w1 = (const float*)d_in[1];
    const float* b1 = (const float*)d_in[2];
    const float* w2 = (const float*)d_in[3];
    const float* b2 = (const float*)d_in[4];
    float* out = (float*)d_out;

    float* gap    = (float*)d_ws;            // NB*CIN  = 16384 floats
    float* h      = gap + NB * CIN;          // NB*MID2 = 32768 floats
    float* scores = h + NB * MID2;           // NB*MID  = 16384 floats

    k_gap <<<NB * CIN / 2,       256, 0, stream>>>(x, gap);
    k_fc1 <<<NB * MID2 / (4*4),  256, 0, stream>>>(gap, w1, b1, h);
    k_fc2 <<<NB * MID  / (4*4),  256, 0, stream>>>(h, w2, b2, scores);
    k_mask<<<NB,                 512, 0, stream>>>(scores, out);
}